// Round 4
// baseline (51.518 us; speedup 1.0000x reference)
//
#include <hip/hip_runtime.h>
#include <math.h>

// GaussianMixtureLoss: loss = CONST - mean_{b,n}( ln sum_m exp(p·g - |g|²/2) - |p|²/2 )
// B=4, N=4096, M=4096, D=3, SIGMA=1.
// Fused single-kernel design: 512 blocks each do a (2048-point x 256-mixture)
// tile, combine across mixture-chunks via device-scope float atomicAdd into
// ws, and the LAST block (completion counter) does log+reduce+writeout.
// Dispatches per call: 1 memset (65 KB) + 1 kernel.
#define BATCH 4
#define NPTS 4096
#define NMIX 4096
#define NCHUNK 16
#define MCHUNK 256          // NMIX / NCHUNK
#define THREADS 256
#define PPT 2               // points per thread
#define TOTAL_BLOCKS ((NPTS / (THREADS * PPT)) * BATCH * NCHUNK)  // 8*4*16 = 512

#define L2E 1.4426950408889634f
#define LN2 0.6931471805599453f
#define CONST_TERM 0.9189385332046727f  // 0.5*log(2*pi)

// ws layout (floats): [0]=counter(uint), [1]=hp2 accum, [16..16+16384)=sums
#define WS_HEADER 16
#define WS_ZERO_BYTES ((WS_HEADER + BATCH * NPTS) * 4)

__device__ __forceinline__ float fast_exp2(float x) {
#if __has_builtin(__builtin_amdgcn_exp2f)
  return __builtin_amdgcn_exp2f(x);
#else
  return exp2f(x);
#endif
}
__device__ __forceinline__ float fast_log2(float x) {
#if __has_builtin(__builtin_amdgcn_logf)
  return __builtin_amdgcn_logf(x);
#else
  return log2f(x);
#endif
}

__global__ __launch_bounds__(THREADS) void gm_fused(
    const float* __restrict__ pred, const float* __restrict__ gt,
    float* __restrict__ out, float* __restrict__ ws) {
  unsigned int* counter = (unsigned int*)ws;
  float* hp2_slot = ws + 1;
  float* sums = ws + WS_HEADER;

  __shared__ float4 gsh[MCHUNK];  // (L2E*g, -0.5*L2E*|g|²) : 4 KB
  const int t = threadIdx.x;
  const int b = blockIdx.y;
  const int n0 = blockIdx.x * (THREADS * PPT);
  const int m0 = blockIdx.z * MCHUNK;

  {  // stage mixture chunk, pre-scaled so main loop is 3 FMA + exp per pair
    const float* g = gt + ((size_t)(b * NMIX + m0 + t)) * 3;
    float gx = g[0], gy = g[1], gz = g[2];
    gsh[t] = make_float4(L2E * gx, L2E * gy, L2E * gz,
                         -0.5f * L2E * (gx * gx + gy * gy + gz * gz));
  }

  const float* p0 = pred + ((size_t)(b * NPTS + n0 + t)) * 3;
  const float* p1 = p0 + THREADS * 3;
  const float p0x = p0[0], p0y = p0[1], p0z = p0[2];
  const float p1x = p1[0], p1y = p1[1], p1z = p1[2];
  float acc0 = 0.f, acc1 = 0.f;

  __syncthreads();

#pragma unroll 4
  for (int j = 0; j < MCHUNK; ++j) {
    float4 gv = gsh[j];  // uniform broadcast read, serves 2 pairs
    acc0 += fast_exp2(fmaf(p0x, gv.x, fmaf(p0y, gv.y, fmaf(p0z, gv.z, gv.w))));
    acc1 += fast_exp2(fmaf(p1x, gv.x, fmaf(p1y, gv.y, fmaf(p1z, gv.z, gv.w))));
  }

  const int gp0 = b * NPTS + n0 + t;
  atomicAdd(sums + gp0, acc0);                 // device-scope, coherent point
  atomicAdd(sums + gp0 + THREADS, acc1);

  // one slice accumulates sum of |p|²/2 (linearity: pull it out of the mean)
  if (blockIdx.z == 0) {
    float h = 0.5f * (p0x * p0x + p0y * p0y + p0z * p0z) +
              0.5f * (p1x * p1x + p1y * p1y + p1z * p1z);
    for (int off = 32; off > 0; off >>= 1) h += __shfl_down(h, off, 64);
    if ((t & 63) == 0) atomicAdd(hp2_slot, h);
  }

  // completion protocol: make this block's atomics visible, then count
  __threadfence();
  __syncthreads();
  __shared__ int lastflag;
  if (t == 0) {
    unsigned int old = atomicAdd(counter, 1u);
    lastflag = (old == TOTAL_BLOCKS - 1) ? 1 : 0;
  }
  __syncthreads();
  if (!lastflag) return;

  // ---- tail: only the last-finishing block runs this ----
  __threadfence();  // acquire
  float llsum = 0.f;
#pragma unroll
  for (int i = 0; i < (BATCH * NPTS) / THREADS; ++i) {  // 64 coalesced loads
    float s = __hip_atomic_load(sums + i * THREADS + t, __ATOMIC_RELAXED,
                                __HIP_MEMORY_SCOPE_AGENT);
    llsum += fast_log2(s);
  }
  llsum *= LN2;
  for (int off = 32; off > 0; off >>= 1) llsum += __shfl_down(llsum, off, 64);
  __shared__ float wsum[4];
  if ((t & 63) == 0) wsum[t >> 6] = llsum;
  __syncthreads();
  if (t == 0) {
    float h = __hip_atomic_load(hp2_slot, __ATOMIC_RELAXED,
                                __HIP_MEMORY_SCOPE_AGENT);
    float total = ((wsum[0] + wsum[1]) + (wsum[2] + wsum[3])) - h;
    out[0] = CONST_TERM - total * (1.0f / (float)(BATCH * NPTS));
  }
}

extern "C" void kernel_launch(void* const* d_in, const int* in_sizes, int n_in,
                              void* d_out, int out_size, void* d_ws, size_t ws_size,
                              hipStream_t stream) {
  const float* pred = (const float*)d_in[0];
  const float* gt   = (const float*)d_in[1];
  float* out = (float*)d_out;
  float* ws = (float*)d_ws;

  hipMemsetAsync(d_ws, 0, WS_ZERO_BYTES, stream);  // counter + hp2 + sums

  dim3 g1(NPTS / (THREADS * PPT), BATCH, NCHUNK);  // (8, 4, 16) = 512 blocks
  gm_fused<<<g1, THREADS, 0, stream>>>(pred, gt, out, ws);
}

// Round 5
// 20.612 us; speedup vs baseline: 2.4994x; 2.4994x over previous
//
#include <hip/hip_runtime.h>
#include <math.h>

// GaussianMixtureLoss: loss = CONST - mean_{b,n}( ln sum_m exp(p·g - |g|²/2) - |p|²/2 )
// B=4, N=4096, M=4096, D=3, SIGMA=1.
// R5: 2 dispatches, ZERO atomics, no ws init needed.
//  K1: 512 blocks; block = 32 points x 4096 mixtures (full LSE sum in-block).
//      Thread = 4 points x 128 mixtures; mixtures staged in 2 LDS passes.
//  K2: single block reduces the 512 pre-scaled block sums.
#define BATCH 4
#define NPTS 4096
#define NMIX 4096
#define THREADS 256
#define PPB 32               // points per block
#define PPT 4                // points per thread
#define SCH 32               // mixture chunks per block (threads = PPB/PPT * SCH)
#define MSTAGE 2048          // mixtures staged per pass (32 KB)
#define PASSES (NMIX / MSTAGE)
#define MPT (MSTAGE / SCH)   // 64 mixtures per thread per pass
#define NBLOCKS ((BATCH * NPTS) / PPB)  // 512

#define L2E 1.4426950408889634f
#define LN2 0.6931471805599453f
#define CONST_TERM 0.9189385332046727f  // 0.5*log(2*pi)

__device__ __forceinline__ float fast_exp2(float x) {
#if __has_builtin(__builtin_amdgcn_exp2f)
  return __builtin_amdgcn_exp2f(x);   // raw v_exp_f32
#else
  return exp2f(x);
#endif
}
__device__ __forceinline__ float fast_log2(float x) {
#if __has_builtin(__builtin_amdgcn_logf)
  return __builtin_amdgcn_logf(x);    // raw v_log_f32
#else
  return log2f(x);
#endif
}

__global__ __launch_bounds__(THREADS) void gm_main(
    const float* __restrict__ pred, const float* __restrict__ gt,
    float* __restrict__ bsum) {
  __shared__ float4 gsh[MSTAGE];        // 32 KB: (L2E*g, -0.5*L2E*|g|^2)
  __shared__ float comb[SCH][PPB + 1];  // 32x33 padded, conflict-free

  const int t = threadIdx.x;
  const int b = blockIdx.x >> 7;             // 128 blocks per batch
  const int n0 = (blockIdx.x & 127) * PPB;
  const int c = t >> 3;                      // mixture chunk 0..31
  const int pi = (t & 7) * PPT;              // first point 0,4,...,28

  // 4 points in registers
  float px[PPT], py[PPT], pz[PPT], acc[PPT];
#pragma unroll
  for (int k = 0; k < PPT; ++k) {
    const float* p = pred + ((size_t)(b * NPTS + n0 + pi + k)) * 3;
    px[k] = p[0]; py[k] = p[1]; pz[k] = p[2];
    acc[k] = 0.f;
  }

  for (int q = 0; q < PASSES; ++q) {
    __syncthreads();  // prior-pass readers done before restage
#pragma unroll
    for (int k2 = 0; k2 < MSTAGE / THREADS; ++k2) {
      int s = t + k2 * THREADS;
      const float* g = gt + ((size_t)(b * NMIX + q * MSTAGE + s)) * 3;
      float gx = g[0], gy = g[1], gz = g[2];
      gsh[s] = make_float4(L2E * gx, L2E * gy, L2E * gz,
                           -0.5f * L2E * (gx * gx + gy * gy + gz * gz));
    }
    __syncthreads();

    const float4* gp = gsh + c * MPT;
#pragma unroll 4
    for (int j = 0; j < MPT; ++j) {
      float4 gv = gp[j];  // 1 ds_read_b128 serves 4 exps
#pragma unroll
      for (int k = 0; k < PPT; ++k) {
        acc[k] += fast_exp2(
            fmaf(px[k], gv.x, fmaf(py[k], gv.y, fmaf(pz[k], gv.z, gv.w))));
      }
    }
  }

  // in-block combine: comb[chunk][point]
#pragma unroll
  for (int k = 0; k < PPT; ++k) comb[c][pi + k] = acc[k];
  __syncthreads();

  if (t < PPB) {
    float s = 0.f;
#pragma unroll
    for (int cc = 0; cc < SCH; ++cc) s += comb[cc][t];  // conflict-free (pad 33)
    const float* p = pred + ((size_t)(b * NPTS + n0 + t)) * 3;
    float hp2 = 0.5f * (p[0] * p[0] + p[1] * p[1] + p[2] * p[2]);
    float ll = LN2 * fast_log2(s) - hp2;
    for (int off = 16; off > 0; off >>= 1) ll += __shfl_down(ll, off, 64);
    if (t == 0) bsum[blockIdx.x] = ll * (1.0f / (float)(BATCH * NPTS));
  }
}

__global__ __launch_bounds__(THREADS) void gm_reduce(
    const float* __restrict__ bsum, float* __restrict__ out) {
  const int t = threadIdx.x;
  float v = bsum[t] + bsum[t + THREADS];  // 512 entries
  for (int off = 32; off > 0; off >>= 1) v += __shfl_down(v, off, 64);
  __shared__ float w[4];
  if ((t & 63) == 0) w[t >> 6] = v;
  __syncthreads();
  if (t == 0) out[0] = CONST_TERM - ((w[0] + w[1]) + (w[2] + w[3]));
}

extern "C" void kernel_launch(void* const* d_in, const int* in_sizes, int n_in,
                              void* d_out, int out_size, void* d_ws, size_t ws_size,
                              hipStream_t stream) {
  const float* pred = (const float*)d_in[0];
  const float* gt   = (const float*)d_in[1];
  float* out = (float*)d_out;
  float* bsum = (float*)d_ws;  // 512 floats, fully overwritten every call

  gm_main<<<NBLOCKS, THREADS, 0, stream>>>(pred, gt, bsum);
  gm_reduce<<<1, THREADS, 0, stream>>>(bsum, out);
}

// Round 6
// 20.225 us; speedup vs baseline: 2.5473x; 1.0191x over previous
//
#include <hip/hip_runtime.h>
#include <math.h>

// GaussianMixtureLoss: loss = CONST - mean_{b,n}( ln sum_m exp(p·g - |g|²/2) - |p|²/2 )
// B=4, N=4096, M=4096, D=3, SIGMA=1.
// R6: 2 dispatches, no atomics, no ws init.
//  K1: 1024 blocks; block = 16 points x 4096 mixtures (full sum in-block).
//      Thread = 8 points (4x v2f packs, v_pk_fma dot) x 128-mixture chunks,
//      2 LDS passes of 2048 staged mixtures. 4 blocks/CU (LDS aliased tail).
//  K2: single block reduces 1024 pre-scaled block sums.
#define BATCH 4
#define NPTS 4096
#define NMIX 4096
#define THREADS 256
#define PPB 16                // points per block
#define PPT 8                 // points per thread (4x v2f)
#define SCH 128               // mixture chunks per block (PPB/PPT * SCH = 256)
#define MSTAGE 2048           // mixtures staged per pass (32 KB)
#define PASSES (NMIX / MSTAGE)
#define MPT (MSTAGE / SCH)    // 16 mixtures per thread per pass
#define NBLOCKS ((BATCH * NPTS) / PPB)  // 1024

#define L2E 1.4426950408889634f
#define LN2 0.6931471805599453f
#define CONST_TERM 0.9189385332046727f  // 0.5*log(2*pi)
#define INV_COUNT (1.0f / (float)(BATCH * NPTS))

typedef float v2f __attribute__((ext_vector_type(2)));

__device__ __forceinline__ float fast_exp2(float x) {
#if __has_builtin(__builtin_amdgcn_exp2f)
  return __builtin_amdgcn_exp2f(x);   // raw v_exp_f32
#else
  return exp2f(x);
#endif
}
__device__ __forceinline__ float fast_log2(float x) {
#if __has_builtin(__builtin_amdgcn_logf)
  return __builtin_amdgcn_logf(x);    // raw v_log_f32
#else
  return log2f(x);
#endif
}

__global__ __launch_bounds__(THREADS) void gm_main(
    const float* __restrict__ pred, const float* __restrict__ gt,
    float* __restrict__ bsum) {
  __shared__ float4 gsh[MSTAGE];   // 32 KB: (L2E*g, -0.5*L2E*|g|^2)
  __shared__ float wpart[64];      // [4 waves][16 points]
  float* comb = (float*)gsh;       // aliased tail buffer [SCH][PPB+1]=[128][17]

  const int t = threadIdx.x;
  const int b = blockIdx.x >> 8;             // 256 blocks per batch
  const int n0 = (blockIdx.x & 255) * PPB;
  const int c = t >> 1;                      // mixture chunk 0..127
  const int pi = (t & 1) * PPT;              // point base 0 or 8

  // 8 points as 4 v2f packs (adjacent points are contiguous: 6 floats)
  v2f px[4], py[4], pz[4], acc[4];
#pragma unroll
  for (int k = 0; k < 4; ++k) {
    const float* p = pred + ((size_t)(b * NPTS + n0 + pi + 2 * k)) * 3;
    px[k] = (v2f){p[0], p[3]};
    py[k] = (v2f){p[1], p[4]};
    pz[k] = (v2f){p[2], p[5]};
    acc[k] = (v2f){0.f, 0.f};
  }

  for (int q = 0; q < PASSES; ++q) {
    __syncthreads();  // prior-pass readers done before restage
#pragma unroll
    for (int k2 = 0; k2 < MSTAGE / THREADS; ++k2) {
      int s = t + k2 * THREADS;
      const float* g = gt + ((size_t)(b * NMIX + q * MSTAGE + s)) * 3;
      float gx = g[0], gy = g[1], gz = g[2];
      gsh[s] = make_float4(L2E * gx, L2E * gy, L2E * gz,
                           -0.5f * L2E * (gx * gx + gy * gy + gz * gz));
    }
    __syncthreads();

    const float4* gp = gsh + c * MPT;
#pragma unroll 4
    for (int j = 0; j < MPT; ++j) {
      float4 gv = gp[j];  // 1 ds_read_b128 serves 8 exps
      v2f bx = {gv.x, gv.x}, by = {gv.y, gv.y};
      v2f bz = {gv.z, gv.z}, bw = {gv.w, gv.w};
#pragma unroll
      for (int k = 0; k < 4; ++k) {
        v2f d = __builtin_elementwise_fma(px[k], bx,
                __builtin_elementwise_fma(py[k], by,
                __builtin_elementwise_fma(pz[k], bz, bw)));
        acc[k].x += fast_exp2(d.x);
        acc[k].y += fast_exp2(d.y);
      }
    }
  }

  __syncthreads();  // all gsh reads done before aliasing as comb

  // comb[c][pi+j]: strided write, worst 2-way bank alias (free)
#pragma unroll
  for (int k = 0; k < 4; ++k) {
    comb[c * (PPB + 1) + pi + 2 * k]     = acc[k].x;
    comb[c * (PPB + 1) + pi + 2 * k + 1] = acc[k].y;
  }
  __syncthreads();

  // thread t: point p = t&15, chunk-group g = t>>4 (8 chunks each)
  {
    const int p = t & 15, g = t >> 4;
    float s = 0.f;
#pragma unroll
    for (int j = 0; j < 8; ++j) s += comb[(g * 8 + j) * (PPB + 1) + p];
    // reduce across the 4 chunk-groups within this wave (lanes p, p+16, ...)
    s += __shfl_down(s, 32, 64);
    s += __shfl_down(s, 16, 64);
    if ((t & 63) < 16) wpart[(t >> 6) * 16 + (t & 15)] = s;
  }
  __syncthreads();

  if (t < 16) {
    float s = wpart[t] + wpart[16 + t] + wpart[32 + t] + wpart[48 + t];
    const float* p = pred + ((size_t)(b * NPTS + n0 + t)) * 3;
    float hp2 = 0.5f * (p[0] * p[0] + p[1] * p[1] + p[2] * p[2]);
    float ll = (LN2 * fast_log2(s) - hp2) * INV_COUNT;
#pragma unroll
    for (int off = 8; off > 0; off >>= 1) ll += __shfl_down(ll, off, 16);
    if (t == 0) bsum[blockIdx.x] = ll;
  }
}

__global__ __launch_bounds__(THREADS) void gm_reduce(
    const float* __restrict__ bsum, float* __restrict__ out) {
  const int t = threadIdx.x;
  float v = (bsum[t] + bsum[t + 256]) + (bsum[t + 512] + bsum[t + 768]);
  for (int off = 32; off > 0; off >>= 1) v += __shfl_down(v, off, 64);
  __shared__ float w[4];
  if ((t & 63) == 0) w[t >> 6] = v;
  __syncthreads();
  if (t == 0) out[0] = CONST_TERM - ((w[0] + w[1]) + (w[2] + w[3]));
}

extern "C" void kernel_launch(void* const* d_in, const int* in_sizes, int n_in,
                              void* d_out, int out_size, void* d_ws, size_t ws_size,
                              hipStream_t stream) {
  const float* pred = (const float*)d_in[0];
  const float* gt   = (const float*)d_in[1];
  float* out = (float*)d_out;
  float* bsum = (float*)d_ws;  // 1024 floats, fully overwritten every call

  gm_main<<<NBLOCKS, THREADS, 0, stream>>>(pred, gt, bsum);
  gm_reduce<<<1, THREADS, 0, stream>>>(bsum, out);
}